// Round 8
// baseline (270.638 us; speedup 1.0000x reference)
//
#include <hip/hip_runtime.h>

using frag_t = __attribute__((ext_vector_type(8))) short;   // 8 x bf16 (4 VGPRs)
using f32x4  = __attribute__((ext_vector_type(4))) float;   // MFMA C/D

#define L2E 1.4426950408889634f

constexpr int B_  = 2, S_ = 2048, D_ = 1024, H_ = 16, HD_ = 64;
constexpr int M_  = B_ * S_;      // 4096
constexpr float QSCALE = 0.125f * L2E;   // fold softmax log2e into Q

__device__ __forceinline__ ushort f2bf(float f) {
  union { float f; unsigned u; } v; v.f = f;
  unsigned u = v.u;
  unsigned r = (u + 0x7FFFu + ((u >> 16) & 1u)) >> 16;  // round-nearest-even
  return (ushort)r;
}
__device__ __forceinline__ ushort f2bf_fast(float f) {   // round-half-up, 2 VALU ops
  union { float f; unsigned u; } v; v.f = f;
  return (ushort)((v.u + 0x8000u) >> 16);
}

// async 16B/lane global->LDS (lds dest = wave-uniform base + lane*16) [m97]
__device__ __forceinline__ void gld_lds16(const ushort* g, ushort* l) {
  __builtin_amdgcn_global_load_lds((const __attribute__((address_space(1))) void*)g,
                                   (__attribute__((address_space(3))) void*)l, 16, 0, 0);
}

// ---------- fused prep: x->bf16  |  Wqkv^T->bf16  |  Wproj^T->bf16 ----------
__global__ __launch_bounds__(256) void k_prep(
    const float* __restrict__ x, const float* __restrict__ Wqkv,
    const float* __restrict__ Wproj,
    ushort* __restrict__ Xbf, ushort* __restrict__ Wqt, ushort* __restrict__ Wpt) {
  int blk = blockIdx.x, tid = threadIdx.x;
  if (blk < 1024) {                                 // x convert: 4096 elems/block
    size_t base = (size_t)blk * 4096 + tid * 4;
    #pragma unroll
    for (int i = 0; i < 4; ++i) {
      float4 f = *(const float4*)(x + base + i * 1024);
      ushort4 o;
      o.x = f2bf(f.x); o.y = f2bf(f.y); o.z = f2bf(f.z); o.w = f2bf(f.w);
      *(ushort4*)(Xbf + base + i * 1024) = o;
    }
  } else {                                          // W [K,N] -> W^T [N,K] bf16, 64x64 tile
    __shared__ float tile[64][65];
    const float* in; ushort* out; int N, K, bx, by;
    if (blk < 1024 + 768) { int b2 = blk - 1024; in = Wqkv;  out = Wqt; N = 3072; K = 1024; bx = b2 % 48; by = b2 / 48; }
    else                  { int b2 = blk - 1792; in = Wproj; out = Wpt; N = 1024; K = 1024; bx = b2 % 16; by = b2 / 16; }
    int n0 = bx * 64, k0 = by * 64;
    int tx = tid & 63, ty = tid >> 6;               // (64,4)
    #pragma unroll
    for (int i = 0; i < 16; ++i)
      tile[ty + i * 4][tx] = in[(size_t)(k0 + ty + i * 4) * N + n0 + tx];
    __syncthreads();
    #pragma unroll
    for (int i = 0; i < 16; ++i)
      out[(size_t)(n0 + ty + i * 4) * K + k0 + tx] = f2bf(tile[tx][ty + i * 4]);
  }
}

// ---------- bf16 MFMA GEMM: C[M,N] = A[M,K] @ Bt[N,K]^T + bias ----------
// Register-staged DOUBLE-BUFFERED K-loop (classic hipBLASLt shape):
//   gload(it+1) -> VGPRs issued before compute(it)  => L2 stream overlaps MFMA
//   (the R4/R6 single-buffer m97 shape serialized a ~1700cyc L2 stream with
//    ~600cyc compute each iter — the invariant ~60us);
//   VGPR -> LDS via ds_write_b128, two __syncthreads/iter, no manual waitcnt.
// Swizzle lives on the ds_write address (global loads naturally coalesced):
// LDS chunk = gchunk ^ (row&7); read slot = (ks*4+quad)^(li&7)  (98k-conflict
// measured pattern from R6).
// EPI 0: BM=128, grid 768; Q(*0.125*log2e)/K head layouts; V via per-wave LDS
//        transpose -> V^T coalesced.  EPI 1: BM=64, grid 512, f32 out.
template <int EPI>
__global__ __launch_bounds__(256) void k_gemm(
    const ushort* __restrict__ A, const ushort* __restrict__ Bt,
    const float* __restrict__ bias,
    ushort* __restrict__ Qo, ushort* __restrict__ Ko, ushort* __restrict__ Vo,
    float* __restrict__ Co, int N, int K) {
  constexpr int BM = (EPI == 0) ? 128 : 64;
  constexpr int BN = 128, BK = 64;
  constexpr int MI = (EPI == 0) ? 4 : 2, NI = 4;
  constexpr int ANI = BM / 32;                      // A gload insts per wave
  __shared__ ushort smem[2 * (BM + BN) * BK];
  ushort* As = smem;                                // As[b] at b*BM*BK
  ushort* Bs = smem + 2 * BM * BK;                  // Bs[b] at b*BN*BK
  int tid  = threadIdx.x;
  int lane = tid & 63, wave = tid >> 6;
  int quad = lane >> 4, li = lane & 15;
  int wy = wave >> 1, wx = wave & 1;                // 2x2 waves
  int mbase = wy * (MI * 16), nbase = wx * 64;
  int m0 = blockIdx.y * BM, n0 = blockIdx.x * BN;
  int srow = lane >> 3, sch = lane & 7;             // 8 rows x 8 chunks(16B) per inst
  int wch  = (sch ^ srow) * 8;                      // swizzled LDS chunk offset
  int niter = K / BK;

  uint4 ar[ANI], br[4];
  auto gload = [&](int it) {
    int k0 = it * BK;
    #pragma unroll
    for (int i = 0; i < ANI; ++i)
      ar[i] = *(const uint4*)&A[(size_t)(m0 + i * 32 + wave * 8 + srow) * K + k0 + sch * 8];
    #pragma unroll
    for (int i = 0; i < 4; ++i)
      br[i] = *(const uint4*)&Bt[(size_t)(n0 + i * 32 + wave * 8 + srow) * K + k0 + sch * 8];
  };
  auto swrite = [&](int b) {
    #pragma unroll
    for (int i = 0; i < ANI; ++i)
      *(uint4*)&As[(size_t)b * BM * BK + (i * 32 + wave * 8 + srow) * BK + wch] = ar[i];
    #pragma unroll
    for (int i = 0; i < 4; ++i)
      *(uint4*)&Bs[(size_t)b * BN * BK + (i * 32 + wave * 8 + srow) * BK + wch] = br[i];
  };

  f32x4 acc[MI][NI] = {};
  gload(0); swrite(0);
  gload(1);                                         // in flight through compute(0)
  for (int it = 0; it < niter; ++it) {
    __syncthreads();                                // buf[it&1] writes visible
    int b = it & 1;
    #pragma unroll
    for (int ks = 0; ks < 2; ++ks) {
      frag_t af[MI], bf[NI];
      #pragma unroll
      for (int mi = 0; mi < MI; ++mi)
        af[mi] = *(const frag_t*)&As[(size_t)b * BM * BK + (mbase + mi * 16 + li) * BK + (((ks * 4 + quad) ^ (li & 7)) * 8)];
      #pragma unroll
      for (int ni = 0; ni < NI; ++ni)
        bf[ni] = *(const frag_t*)&Bs[(size_t)b * BN * BK + (nbase + ni * 16 + li) * BK + (((ks * 4 + quad) ^ (li & 7)) * 8)];
      #pragma unroll
      for (int mi = 0; mi < MI; ++mi)
        #pragma unroll
        for (int ni = 0; ni < NI; ++ni)
          acc[mi][ni] = __builtin_amdgcn_mfma_f32_16x16x32_bf16(af[mi], bf[ni], acc[mi][ni], 0, 0, 0);
    }
    __syncthreads();                                // all waves done reading buf[it&1]
    if (it + 1 < niter) {
      swrite((it + 1) & 1);                         // regs from gload(it+1): had compute(it) to land
      if (it + 2 < niter) gload(it + 2);            // regs free after swrite
    }
  }

  // epilogue: C/D layout row = quad*4+reg, col = li  [measured m89/m91]
  if (EPI == 1) {
    #pragma unroll
    for (int mi = 0; mi < MI; ++mi)
      #pragma unroll
      for (int ni = 0; ni < NI; ++ni) {
        int gcol = n0 + nbase + ni * 16 + li;
        float bv = bias[gcol];
        #pragma unroll
        for (int r = 0; r < 4; ++r) {
          int grow = m0 + mbase + mi * 16 + quad * 4 + r;
          Co[(size_t)grow * N + gcol] = acc[mi][ni][r] + bv;
        }
      }
  } else {
    int which = (n0 + nbase) >> 10;                 // wave-uniform (64-aligned halves)
    if (which < 2) {                                // Q / K: [bh][s][hd]
      #pragma unroll
      for (int mi = 0; mi < MI; ++mi)
        #pragma unroll
        for (int ni = 0; ni < NI; ++ni) {
          int gcol = n0 + nbase + ni * 16 + li;
          float bv = bias[gcol];
          #pragma unroll
          for (int r = 0; r < 4; ++r) {
            int grow = m0 + mbase + mi * 16 + quad * 4 + r;
            float v = acc[mi][ni][r] + bv;
            int d = gcol & 1023, h = d >> 6, hd = d & 63;
            int b = grow >> 11, s = grow & 2047;
            size_t bh = (size_t)b * H_ + h;
            if (which == 0) Qo[(bh * S_ + s) * HD_ + hd] = f2bf(v * QSCALE);
            else            Ko[(bh * S_ + s) * HD_ + hd] = f2bf(v);
          }
        }
    } else {                                        // V: per-wave LDS transpose -> coalesced V^T
      __syncthreads();                              // staging LDS dead now
      ushort* vlds = smem + wave * (64 * 72);
      #pragma unroll
      for (int ni = 0; ni < NI; ++ni) {
        float bv = bias[n0 + nbase + ni * 16 + li];
        #pragma unroll
        for (int mi = 0; mi < MI; ++mi)
          #pragma unroll
          for (int r = 0; r < 4; ++r)
            vlds[(ni * 16 + li) * 72 + mi * 16 + quad * 4 + r] = f2bf(acc[mi][ni][r] + bv);
      }                                             // wave-private: in-order ds, no barrier
      int hgrp = ((n0 & 1023) + nbase) >> 6;
      int b = m0 >> 11;
      int s0 = (m0 & 2047) + mbase;
      size_t vbase = (size_t)(b * H_ + hgrp) * HD_ * S_;
      #pragma unroll
      for (int i = 0; i < 8; ++i) {
        int row = i * 8 + (lane >> 3);              // hd
        int col = (lane & 7) * 8;                   // s offset, 16B aligned
        *(uint4*)&Vo[vbase + (size_t)row * S_ + s0 + col] = *(const uint4*)&vlds[row * 72 + col];
      }
    }
  }
}

// ---------- causal flash attention (unchanged from R6) ----------
__global__ __launch_bounds__(256) void k_attn(
    const ushort* __restrict__ Q, const ushort* __restrict__ K,
    const ushort* __restrict__ Vt, ushort* __restrict__ O) {
  __shared__ ushort Kbuf[2][64 * 64];
  __shared__ ushort Vbuf[2][64 * 64];
  __shared__ ushort Plds[4 * 16 * 64];             // per-wave P buffer (C->A transform)
  int lane = threadIdx.x & 63, wave = threadIdx.x >> 6;
  int quad = lane >> 4, li = lane & 15;
  int bh = blockIdx.x;                             // x = bh: XCD round-robin, K/V hot in L2
  int qb = 31 - (int)blockIdx.y;                   // heavy q-tiles dispatch first
  int b = bh >> 4, h = bh & 15;
  int q0 = qb * 64 + wave * 16;
  const ushort* Qb = Q  + (size_t)bh * S_ * HD_;
  const ushort* Kb = K  + (size_t)bh * S_ * HD_;
  const ushort* Vb = Vt + (size_t)bh * HD_ * S_;
  ushort* Pw = &Plds[wave * 1024];

  frag_t qf[2];  // A-operand: m = li, k = quad*8+j  [measured m120]
  #pragma unroll
  for (int ks = 0; ks < 2; ++ks)
    qf[ks] = *(const frag_t*)&Qb[(size_t)(q0 + li) * HD_ + ks * 32 + quad * 8];

  f32x4 o[4] = {};
  float l_r[4] = {0.f, 0.f, 0.f, 0.f};

  auto stage = [&](int kb, int bi) {
    #pragma unroll
    for (int i = 0; i < 2; ++i) {
      int rt  = wave * 16 + i * 8 + (lane >> 3);   // tile row
      int c16 = (lane & 7) ^ (lane >> 3);          // swizzle: (rt&7) == lane>>3
      gld_lds16(&Kb[(size_t)(kb * 64 + rt) * HD_ + c16 * 8], &Kbuf[bi][(wave * 16 + i * 8) * 64]);
      gld_lds16(&Vb[(size_t)rt * S_ + kb * 64 + c16 * 8],    &Vbuf[bi][(wave * 16 + i * 8) * 64]);
    }
  };

  auto comp = [&](int kb, bool diag, int bi) {
    f32x4 sc[4];
    #pragma unroll
    for (int t = 0; t < 4; ++t) {
      f32x4 a = {};
      #pragma unroll
      for (int ks = 0; ks < 2; ++ks) {
        frag_t kf = *(const frag_t*)&Kbuf[bi][(t * 16 + li) * 64 + (((quad + ks * 4) ^ (li & 7)) * 8)];
        a = __builtin_amdgcn_mfma_f32_16x16x32_bf16(qf[ks], kf, a, 0, 0, 0);
      }
      sc[t] = a;
    }
    if (diag) {
      #pragma unroll
      for (int t = 0; t < 4; ++t) {
        int key = kb * 64 + t * 16 + li;
        #pragma unroll
        for (int r = 0; r < 4; ++r)
          if (key > q0 + quad * 4 + r) sc[t][r] = -1e30f;
      }
    }
    #pragma unroll
    for (int t = 0; t < 4; ++t)
      #pragma unroll
      for (int r = 0; r < 4; ++r) {
        float p = exp2f(sc[t][r]);                 // log2e folded into Q; masked -> 0
        l_r[r] += p;
        int row = quad * 4 + r;
        int swr = ((row >> 2) << 1) | (row & 1);
        Pw[row * 64 + (((t * 2 + (li >> 3)) ^ swr) * 8) + (li & 7)] = f2bf_fast(p);
      }
    frag_t pf[2];                                  // wave-private LDS: in-order, no barrier
    int swl = ((li >> 2) << 1) | (li & 1);
    #pragma unroll
    for (int ks = 0; ks < 2; ++ks)
      pf[ks] = *(const frag_t*)&Pw[li * 64 + (((ks * 4 + quad) ^ swl) * 8)];
    #pragma unroll
    for (int t = 0; t < 4; ++t)
      #pragma unroll
      for (int ks = 0; ks < 2; ++ks) {
        frag_t vf = *(const frag_t*)&Vbuf[bi][(t * 16 + li) * 64 + (((quad + ks * 4) ^ (li & 7)) * 8)];
        o[t] = __builtin_amdgcn_mfma_f32_16x16x32_bf16(pf[ks], vf, o[t], 0, 0, 0);
      }
  };

  stage(0, 0);
  __syncthreads();                                 // DMA for kb=0 landed
  for (int kb = 0; kb <= qb; ++kb) {
    if (kb < qb) stage(kb + 1, (kb + 1) & 1);      // async DMA overlaps comp below
    comp(kb, kb == qb, kb & 1);
    __syncthreads();                               // drains DMA + guards buffer reuse
  }

  #pragma unroll
  for (int r = 0; r < 4; ++r) {
    float t = l_r[r];                              // one reduce per tile
    #pragma unroll
    for (int off = 1; off < 16; off <<= 1) t += __shfl_xor(t, off);
    float inv = 1.f / t;
    int srow = q0 + quad * 4 + r;
    #pragma unroll
    for (int ht = 0; ht < 4; ++ht)
      O[((size_t)b * S_ + srow) * D_ + h * 64 + ht * 16 + li] = f2bf(o[ht][r] * inv);
  }
}

extern "C" void kernel_launch(void* const* d_in, const int* in_sizes, int n_in,
                              void* d_out, int out_size, void* d_ws, size_t ws_size,
                              hipStream_t stream) {
  (void)in_sizes; (void)n_in; (void)out_size; (void)ws_size;
  const float* x     = (const float*)d_in[0];
  const float* Wqkv  = (const float*)d_in[1];
  const float* bqkv  = (const float*)d_in[2];
  const float* Wproj = (const float*)d_in[3];
  const float* bproj = (const float*)d_in[4];
  float* out = (float*)d_out;

  char* ws = (char*)d_ws;                          // 40 MB used
  ushort* Xbf = (ushort*)(ws);                     //  8 MB  [4096,1024] bf16 (reused as O after attn)
  ushort* Wqt = (ushort*)(ws + (8u  << 20));       //  6 MB  [3072,1024] bf16
  ushort* Wpt = (ushort*)(ws + (14u << 20));       //  2 MB  [1024,1024] bf16
  ushort* Qbf = (ushort*)(ws + (16u << 20));       //  8 MB  [32,2048,64]  (pre-scaled by 0.125*log2e)
  ushort* Kbf = (ushort*)(ws + (24u << 20));       //  8 MB  [32,2048,64]
  ushort* Vtb = (ushort*)(ws + (32u << 20));       //  8 MB  [32,64,2048]  (transposed)
  ushort* Obf = Xbf;                               // X dead after QKV GEMM

  k_prep<<<dim3(2048), dim3(256), 0, stream>>>(x, Wqkv, Wproj, Xbf, Wqt, Wpt);
  k_gemm<0><<<dim3(24, 32), dim3(256), 0, stream>>>(Xbf, Wqt, bqkv, Qbf, Kbf, Vtb,
                                                    (float*)nullptr, 3 * D_, D_);
  k_attn<<<dim3(B_ * H_, 32), dim3(256), 0, stream>>>(Qbf, Kbf, Vtb, Obf);
  k_gemm<1><<<dim3(8, 64), dim3(256), 0, stream>>>(Obf, Wpt, bproj,
                                                   (ushort*)nullptr, (ushort*)nullptr, (ushort*)nullptr,
                                                   out, D_, D_);
}

// Round 9
// 187.407 us; speedup vs baseline: 1.4441x; 1.4441x over previous
//
#include <hip/hip_runtime.h>

using frag_t = __attribute__((ext_vector_type(8))) short;   // 8 x bf16 (4 VGPRs)
using f32x4  = __attribute__((ext_vector_type(4))) float;   // MFMA C/D

#define L2E 1.4426950408889634f

constexpr int B_  = 2, S_ = 2048, D_ = 1024, H_ = 16, HD_ = 64;
constexpr int M_  = B_ * S_;      // 4096
constexpr float QSCALE = 0.125f * L2E;   // fold softmax log2e into Q

__device__ __forceinline__ ushort f2bf(float f) {
  union { float f; unsigned u; } v; v.f = f;
  unsigned u = v.u;
  unsigned r = (u + 0x7FFFu + ((u >> 16) & 1u)) >> 16;  // round-nearest-even
  return (ushort)r;
}
__device__ __forceinline__ ushort f2bf_fast(float f) {   // round-half-up, 2 VALU ops
  union { float f; unsigned u; } v; v.f = f;
  return (ushort)((v.u + 0x8000u) >> 16);
}

// async 16B/lane global->LDS (lds dest = wave-uniform base + lane*16) [m97]
__device__ __forceinline__ void gld_lds16(const ushort* g, ushort* l) {
  __builtin_amdgcn_global_load_lds((const __attribute__((address_space(1))) void*)g,
                                   (__attribute__((address_space(3))) void*)l, 16, 0, 0);
}

// ---------- fused prep: x->bf16  |  Wqkv^T->bf16  |  Wproj^T->bf16 ----------
__global__ __launch_bounds__(256) void k_prep(
    const float* __restrict__ x, const float* __restrict__ Wqkv,
    const float* __restrict__ Wproj,
    ushort* __restrict__ Xbf, ushort* __restrict__ Wqt, ushort* __restrict__ Wpt) {
  int blk = blockIdx.x, tid = threadIdx.x;
  if (blk < 1024) {                                 // x convert: 4096 elems/block
    size_t base = (size_t)blk * 4096 + tid * 4;
    #pragma unroll
    for (int i = 0; i < 4; ++i) {
      float4 f = *(const float4*)(x + base + i * 1024);
      ushort4 o;
      o.x = f2bf(f.x); o.y = f2bf(f.y); o.z = f2bf(f.z); o.w = f2bf(f.w);
      *(ushort4*)(Xbf + base + i * 1024) = o;
    }
  } else {                                          // W [K,N] -> W^T [N,K] bf16, 64x64 tile
    __shared__ float tile[64][65];
    const float* in; ushort* out; int N, K, bx, by;
    if (blk < 1024 + 768) { int b2 = blk - 1024; in = Wqkv;  out = Wqt; N = 3072; K = 1024; bx = b2 % 48; by = b2 / 48; }
    else                  { int b2 = blk - 1792; in = Wproj; out = Wpt; N = 1024; K = 1024; bx = b2 % 16; by = b2 / 16; }
    int n0 = bx * 64, k0 = by * 64;
    int tx = tid & 63, ty = tid >> 6;               // (64,4)
    #pragma unroll
    for (int i = 0; i < 16; ++i)
      tile[ty + i * 4][tx] = in[(size_t)(k0 + ty + i * 4) * N + n0 + tx];
    __syncthreads();
    #pragma unroll
    for (int i = 0; i < 16; ++i)
      out[(size_t)(n0 + ty + i * 4) * K + k0 + tx] = f2bf(tile[tx][ty + i * 4]);
  }
}

// ---------- bf16 MFMA GEMM: C[M,N] = A[M,K] @ Bt[N,K]^T + bias ----------
// Validated structure (R4-R6): m97 single-buffer K-loop, global_load_lds
// width=16 staging, XOR chunk swizzle (98k conflicts). Pipelining variants
// (R7 3-stage vmcnt, R8 register dbuf) both regressed — the barrier drain
// is structural to this shape (guide m131-m141); do not re-attempt.
// EPI 0: BM=128, grid 768 (3 WG/CU); Q(*0.125*log2e)/K head layouts; V via
//        per-wave LDS transpose -> V^T coalesced.
// EPI 1: BM=64, grid 512 (2 WG/CU — was 1 at BM=128), f32 out.
template <int EPI>
__global__ __launch_bounds__(256) void k_gemm(
    const ushort* __restrict__ A, const ushort* __restrict__ Bt,
    const float* __restrict__ bias,
    ushort* __restrict__ Qo, ushort* __restrict__ Ko, ushort* __restrict__ Vo,
    float* __restrict__ Co, int N, int K) {
  constexpr int BM = (EPI == 0) ? 128 : 64;
  constexpr int BN = 128, BK = 64;
  constexpr int MI = 4, NI = (EPI == 0) ? 4 : 2;
  constexpr int SMEM = (EPI == 0) ? 4 * 64 * 72 : (BM + BN) * BK;  // EPI0: V-transpose overlay
  __shared__ ushort smem[SMEM];
  ushort* As = smem;
  ushort* Bs = smem + BM * BK;
  int tid  = threadIdx.x;
  int lane = tid & 63, wave = tid >> 6;
  int quad = lane >> 4, li = lane & 15;
  int mbase = (EPI == 0) ? (wave >> 1) * 64 : 0;    // EPI0: 2x2 waves; EPI1: N-split only
  int nbase = (EPI == 0) ? (wave & 1) * 64 : wave * 32;
  int m0 = blockIdx.y * BM, n0 = blockIdx.x * BN;
  int srow = lane >> 3;                             // within a wave: 8 rows x 128B
  int scol = ((lane & 7) ^ srow) * 8;               // XOR-swizzled global chunk
  f32x4 acc[MI][NI] = {};
  for (int k0 = 0; k0 < K; k0 += BK) {
    if (EPI == 0) {
      #pragma unroll
      for (int i = 0; i < 4; ++i) {
        int rbase = i * 32 + wave * 8;              // wave-uniform LDS row base (mult of 8)
        int r = rbase + srow;
        gld_lds16(&A[(size_t)(m0 + r) * K + k0 + scol], &As[rbase * BK]);
        gld_lds16(&Bt[(size_t)(n0 + r) * K + k0 + scol], &Bs[rbase * BK]);
      }
    } else {
      #pragma unroll
      for (int i = 0; i < 2; ++i) {                 // A: 64 rows
        int rbase = wave * 16 + i * 8;
        gld_lds16(&A[(size_t)(m0 + rbase + srow) * K + k0 + scol], &As[rbase * BK]);
      }
      #pragma unroll
      for (int i = 0; i < 4; ++i) {                 // B: 128 rows
        int rbase = i * 32 + wave * 8;
        gld_lds16(&Bt[(size_t)(n0 + rbase + srow) * K + k0 + scol], &Bs[rbase * BK]);
      }
    }
    __syncthreads();                                // drains vmcnt (compiler-emitted)
    #pragma unroll
    for (int ks = 0; ks < 2; ++ks) {
      frag_t af[MI], bf[NI];
      #pragma unroll
      for (int mi = 0; mi < MI; ++mi)
        af[mi] = *(const frag_t*)&As[(mbase + mi * 16 + li) * BK + (((ks * 4 + quad) ^ (li & 7)) * 8)];
      #pragma unroll
      for (int ni = 0; ni < NI; ++ni)
        bf[ni] = *(const frag_t*)&Bs[(nbase + ni * 16 + li) * BK + (((ks * 4 + quad) ^ (li & 7)) * 8)];
      #pragma unroll
      for (int mi = 0; mi < MI; ++mi)
        #pragma unroll
        for (int ni = 0; ni < NI; ++ni)
          acc[mi][ni] = __builtin_amdgcn_mfma_f32_16x16x32_bf16(af[mi], bf[ni], acc[mi][ni], 0, 0, 0);
    }
    __syncthreads();
  }
  // epilogue: C/D layout row = quad*4+reg, col = li  [measured m89/m91]
  if (EPI == 1) {
    #pragma unroll
    for (int mi = 0; mi < MI; ++mi)
      #pragma unroll
      for (int ni = 0; ni < NI; ++ni) {
        int gcol = n0 + nbase + ni * 16 + li;
        float bv = bias[gcol];
        #pragma unroll
        for (int r = 0; r < 4; ++r) {
          int grow = m0 + mbase + mi * 16 + quad * 4 + r;
          Co[(size_t)grow * N + gcol] = acc[mi][ni][r] + bv;
        }
      }
  } else {
    int which = (n0 + nbase) >> 10;                 // wave-uniform (64-aligned halves)
    if (which < 2) {                                // Q / K: [bh][s][hd]
      #pragma unroll
      for (int mi = 0; mi < MI; ++mi)
        #pragma unroll
        for (int ni = 0; ni < NI; ++ni) {
          int gcol = n0 + nbase + ni * 16 + li;
          float bv = bias[gcol];
          #pragma unroll
          for (int r = 0; r < 4; ++r) {
            int grow = m0 + mbase + mi * 16 + quad * 4 + r;
            float v = acc[mi][ni][r] + bv;
            int d = gcol & 1023, h = d >> 6, hd = d & 63;
            int b = grow >> 11, s = grow & 2047;
            size_t bh = (size_t)b * H_ + h;
            if (which == 0) Qo[(bh * S_ + s) * HD_ + hd] = f2bf(v * QSCALE);
            else            Ko[(bh * S_ + s) * HD_ + hd] = f2bf(v);
          }
        }
    } else {                                        // V: per-wave LDS transpose -> coalesced V^T
      ushort* vlds = smem + wave * (64 * 72);       // staging LDS dead after last barrier
      #pragma unroll
      for (int ni = 0; ni < NI; ++ni) {
        float bv = bias[n0 + nbase + ni * 16 + li];
        #pragma unroll
        for (int mi = 0; mi < MI; ++mi)
          #pragma unroll
          for (int r = 0; r < 4; ++r)
            vlds[(ni * 16 + li) * 72 + mi * 16 + quad * 4 + r] = f2bf(acc[mi][ni][r] + bv);
      }                                             // wave-private: in-order ds, no barrier
      int hgrp = ((n0 & 1023) + nbase) >> 6;
      int b = m0 >> 11;
      int s0 = (m0 & 2047) + mbase;
      size_t vbase = (size_t)(b * H_ + hgrp) * HD_ * S_;
      #pragma unroll
      for (int i = 0; i < 8; ++i) {
        int row = i * 8 + (lane >> 3);              // hd
        int col = (lane & 7) * 8;                   // s offset, 16B aligned
        *(uint4*)&Vo[vbase + (size_t)row * S_ + s0 + col] = *(const uint4*)&vlds[row * 72 + col];
      }
    }
  }
}

// ---------- causal flash attention (validated R6-R8 version) ----------
// WG = 4 waves = one 64-row q-tile. K/V staged once per WG into double-
// buffered LDS via async global_load_lds. LDS = 40960 B -> 4 WGs/CU.
// K/V chunk16-XOR swizzle; Plds stride 64 w/ row-derived XOR.
// Fixed-max softmax (scores bounded ~N(0,1)); log2e pre-folded into Q.
__global__ __launch_bounds__(256) void k_attn(
    const ushort* __restrict__ Q, const ushort* __restrict__ K,
    const ushort* __restrict__ Vt, ushort* __restrict__ O) {
  __shared__ ushort Kbuf[2][64 * 64];
  __shared__ ushort Vbuf[2][64 * 64];
  __shared__ ushort Plds[4 * 16 * 64];             // per-wave P buffer (C->A transform)
  int lane = threadIdx.x & 63, wave = threadIdx.x >> 6;
  int quad = lane >> 4, li = lane & 15;
  int bh = blockIdx.x;                             // x = bh: XCD round-robin, K/V hot in L2
  int qb = 31 - (int)blockIdx.y;                   // heavy q-tiles dispatch first
  int b = bh >> 4, h = bh & 15;
  int q0 = qb * 64 + wave * 16;
  const ushort* Qb = Q  + (size_t)bh * S_ * HD_;
  const ushort* Kb = K  + (size_t)bh * S_ * HD_;
  const ushort* Vb = Vt + (size_t)bh * HD_ * S_;
  ushort* Pw = &Plds[wave * 1024];

  frag_t qf[2];  // A-operand: m = li, k = quad*8+j  [measured m120]
  #pragma unroll
  for (int ks = 0; ks < 2; ++ks)
    qf[ks] = *(const frag_t*)&Qb[(size_t)(q0 + li) * HD_ + ks * 32 + quad * 8];

  f32x4 o[4] = {};
  float l_r[4] = {0.f, 0.f, 0.f, 0.f};

  auto stage = [&](int kb, int bi) {
    #pragma unroll
    for (int i = 0; i < 2; ++i) {
      int rt  = wave * 16 + i * 8 + (lane >> 3);   // tile row
      int c16 = (lane & 7) ^ (lane >> 3);          // swizzle: (rt&7) == lane>>3
      gld_lds16(&Kb[(size_t)(kb * 64 + rt) * HD_ + c16 * 8], &Kbuf[bi][(wave * 16 + i * 8) * 64]);
      gld_lds16(&Vb[(size_t)rt * S_ + kb * 64 + c16 * 8],    &Vbuf[bi][(wave * 16 + i * 8) * 64]);
    }
  };

  auto comp = [&](int kb, bool diag, int bi) {
    f32x4 sc[4];
    #pragma unroll
    for (int t = 0; t < 4; ++t) {
      f32x4 a = {};
      #pragma unroll
      for (int ks = 0; ks < 2; ++ks) {
        frag_t kf = *(const frag_t*)&Kbuf[bi][(t * 16 + li) * 64 + (((quad + ks * 4) ^ (li & 7)) * 8)];
        a = __builtin_amdgcn_mfma_f32_16x16x32_bf16(qf[ks], kf, a, 0, 0, 0);
      }
      sc[t] = a;
    }
    if (diag) {
      #pragma unroll
      for (int t = 0; t < 4; ++t) {
        int key = kb * 64 + t * 16 + li;
        #pragma unroll
        for (int r = 0; r < 4; ++r)
          if (key > q0 + quad * 4 + r) sc[t][r] = -1e30f;
      }
    }
    #pragma unroll
    for (int t = 0; t < 4; ++t)
      #pragma unroll
      for (int r = 0; r < 4; ++r) {
        float p = exp2f(sc[t][r]);                 // log2e folded into Q; masked -> 0
        l_r[r] += p;
        int row = quad * 4 + r;
        int swr = ((row >> 2) << 1) | (row & 1);
        Pw[row * 64 + (((t * 2 + (li >> 3)) ^ swr) * 8) + (li & 7)] = f2bf_fast(p);
      }
    frag_t pf[2];                                  // wave-private LDS: in-order, no barrier
    int swl = ((li >> 2) << 1) | (li & 1);
    #pragma unroll
    for (int ks = 0; ks < 2; ++ks)
      pf[ks] = *(const frag_t*)&Pw[li * 64 + (((ks * 4 + quad) ^ swl) * 8)];
    #pragma unroll
    for (int t = 0; t < 4; ++t)
      #pragma unroll
      for (int ks = 0; ks < 2; ++ks) {
        frag_t vf = *(const frag_t*)&Vbuf[bi][(t * 16 + li) * 64 + (((quad + ks * 4) ^ (li & 7)) * 8)];
        o[t] = __builtin_amdgcn_mfma_f32_16x16x32_bf16(pf[ks], vf, o[t], 0, 0, 0);
      }
  };

  stage(0, 0);
  __syncthreads();                                 // DMA for kb=0 landed
  for (int kb = 0; kb <= qb; ++kb) {
    if (kb < qb) stage(kb + 1, (kb + 1) & 1);      // async DMA overlaps comp below
    comp(kb, kb == qb, kb & 1);
    __syncthreads();                               // drains DMA + guards buffer reuse
  }

  #pragma unroll
  for (int r = 0; r < 4; ++r) {
    float t = l_r[r];                              // one reduce per tile
    #pragma unroll
    for (int off = 1; off < 16; off <<= 1) t += __shfl_xor(t, off);
    float inv = 1.f / t;
    int srow = q0 + quad * 4 + r;
    #pragma unroll
    for (int ht = 0; ht < 4; ++ht)
      O[((size_t)b * S_ + srow) * D_ + h * 64 + ht * 16 + li] = f2bf(o[ht][r] * inv);
  }
}

extern "C" void kernel_launch(void* const* d_in, const int* in_sizes, int n_in,
                              void* d_out, int out_size, void* d_ws, size_t ws_size,
                              hipStream_t stream) {
  (void)in_sizes; (void)n_in; (void)out_size; (void)ws_size;
  const float* x     = (const float*)d_in[0];
  const float* Wqkv  = (const float*)d_in[1];
  const float* bqkv  = (const float*)d_in[2];
  const float* Wproj = (const float*)d_in[3];
  const float* bproj = (const float*)d_in[4];
  float* out = (float*)d_out;

  char* ws = (char*)d_ws;                          // 40 MB used
  ushort* Xbf = (ushort*)(ws);                     //  8 MB  [4096,1024] bf16 (reused as O after attn)
  ushort* Wqt = (ushort*)(ws + (8u  << 20));       //  6 MB  [3072,1024] bf16
  ushort* Wpt = (ushort*)(ws + (14u << 20));       //  2 MB  [1024,1024] bf16
  ushort* Qbf = (ushort*)(ws + (16u << 20));       //  8 MB  [32,2048,64]  (pre-scaled by 0.125*log2e)
  ushort* Kbf = (ushort*)(ws + (24u << 20));       //  8 MB  [32,2048,64]
  ushort* Vtb = (ushort*)(ws + (32u << 20));       //  8 MB  [32,64,2048]  (transposed)
  ushort* Obf = Xbf;                               // X dead after QKV GEMM

  k_prep<<<dim3(2048), dim3(256), 0, stream>>>(x, Wqkv, Wproj, Xbf, Wqt, Wpt);
  k_gemm<0><<<dim3(24, 32), dim3(256), 0, stream>>>(Xbf, Wqt, bqkv, Qbf, Kbf, Vtb,
                                                    (float*)nullptr, 3 * D_, D_);
  k_attn<<<dim3(B_ * H_, 32), dim3(256), 0, stream>>>(Qbf, Kbf, Vtb, Obf);
  k_gemm<1><<<dim3(8, 64), dim3(256), 0, stream>>>(Obf, Wpt, bproj,
                                                   (ushort*)nullptr, (ushort*)nullptr, (ushort*)nullptr,
                                                   out, D_, D_);
}

// Round 10
// 179.957 us; speedup vs baseline: 1.5039x; 1.0414x over previous
//
#include <hip/hip_runtime.h>

using frag_t = __attribute__((ext_vector_type(8))) short;   // 8 x bf16 (4 VGPRs)
using f32x4  = __attribute__((ext_vector_type(4))) float;   // MFMA C/D

#define L2E 1.4426950408889634f

#if __has_builtin(__builtin_amdgcn_exp2f)
#define EXP2(x) __builtin_amdgcn_exp2f(x)   // raw v_exp_f32 (no denormal fixup seq)
#else
#define EXP2(x) exp2f(x)
#endif

constexpr int B_  = 2, S_ = 2048, D_ = 1024, H_ = 16, HD_ = 64;
constexpr int M_  = B_ * S_;      // 4096
constexpr float QSCALE = 0.125f * L2E;   // fold softmax log2e into Q

__device__ __forceinline__ ushort f2bf(float f) {
  union { float f; unsigned u; } v; v.f = f;
  unsigned u = v.u;
  unsigned r = (u + 0x7FFFu + ((u >> 16) & 1u)) >> 16;  // round-nearest-even
  return (ushort)r;
}

// async 16B/lane global->LDS (lds dest = wave-uniform base + lane*16) [m97]
__device__ __forceinline__ void gld_lds16(const ushort* g, ushort* l) {
  __builtin_amdgcn_global_load_lds((const __attribute__((address_space(1))) void*)g,
                                   (__attribute__((address_space(3))) void*)l, 16, 0, 0);
}

// ---------- fused prep: x->bf16  |  Wqkv^T->bf16  |  Wproj^T->bf16 ----------
__global__ __launch_bounds__(256) void k_prep(
    const float* __restrict__ x, const float* __restrict__ Wqkv,
    const float* __restrict__ Wproj,
    ushort* __restrict__ Xbf, ushort* __restrict__ Wqt, ushort* __restrict__ Wpt) {
  int blk = blockIdx.x, tid = threadIdx.x;
  if (blk < 1024) {                                 // x convert: 4096 elems/block
    size_t base = (size_t)blk * 4096 + tid * 4;
    #pragma unroll
    for (int i = 0; i < 4; ++i) {
      float4 f = *(const float4*)(x + base + i * 1024);
      ushort4 o;
      o.x = f2bf(f.x); o.y = f2bf(f.y); o.z = f2bf(f.z); o.w = f2bf(f.w);
      *(ushort4*)(Xbf + base + i * 1024) = o;
    }
  } else {                                          // W [K,N] -> W^T [N,K] bf16, 64x64 tile
    __shared__ float tile[64][65];
    const float* in; ushort* out; int N, K, bx, by;
    if (blk < 1024 + 768) { int b2 = blk - 1024; in = Wqkv;  out = Wqt; N = 3072; K = 1024; bx = b2 % 48; by = b2 / 48; }
    else                  { int b2 = blk - 1792; in = Wproj; out = Wpt; N = 1024; K = 1024; bx = b2 % 16; by = b2 / 16; }
    int n0 = bx * 64, k0 = by * 64;
    int tx = tid & 63, ty = tid >> 6;               // (64,4)
    #pragma unroll
    for (int i = 0; i < 16; ++i)
      tile[ty + i * 4][tx] = in[(size_t)(k0 + ty + i * 4) * N + n0 + tx];
    __syncthreads();
    #pragma unroll
    for (int i = 0; i < 16; ++i)
      out[(size_t)(n0 + ty + i * 4) * K + k0 + tx] = f2bf(tile[tx][ty + i * 4]);
  }
}

// ---------- bf16 MFMA GEMM: C[M,N] = A[M,K] @ Bt[N,K]^T + bias ----------
// Validated m97 single-buffer K-loop + XOR chunk swizzle (R4-R6; pipelining
// variants R7/R8 regressed — structural, do not re-attempt).
// EPI 0: BM=128, grid 768; Q(*0.125*log2e)/K head layouts; V^T stored with
//        sigma-permuted key order within each 64-block (sigma(p)=16(p&3)+(p>>2))
//        so k_attn can pack P-stores — permutation baked into vlds col index.
// EPI 1: BM=64, grid 512 (2 WG/CU), f32 out.
template <int EPI>
__global__ __launch_bounds__(256) void k_gemm(
    const ushort* __restrict__ A, const ushort* __restrict__ Bt,
    const float* __restrict__ bias,
    ushort* __restrict__ Qo, ushort* __restrict__ Ko, ushort* __restrict__ Vo,
    float* __restrict__ Co, int N, int K) {
  constexpr int BM = (EPI == 0) ? 128 : 64;
  constexpr int BN = 128, BK = 64;
  constexpr int MI = 4, NI = (EPI == 0) ? 4 : 2;
  constexpr int SMEM = (EPI == 0) ? 4 * 64 * 72 : (BM + BN) * BK;  // EPI0: V-transpose overlay
  __shared__ ushort smem[SMEM];
  ushort* As = smem;
  ushort* Bs = smem + BM * BK;
  int tid  = threadIdx.x;
  int lane = tid & 63, wave = tid >> 6;
  int quad = lane >> 4, li = lane & 15;
  int mbase = (EPI == 0) ? (wave >> 1) * 64 : 0;    // EPI0: 2x2 waves; EPI1: N-split only
  int nbase = (EPI == 0) ? (wave & 1) * 64 : wave * 32;
  int m0 = blockIdx.y * BM, n0 = blockIdx.x * BN;
  int srow = lane >> 3;                             // within a wave: 8 rows x 128B
  int scol = ((lane & 7) ^ srow) * 8;               // XOR-swizzled global chunk
  f32x4 acc[MI][NI] = {};
  for (int k0 = 0; k0 < K; k0 += BK) {
    if (EPI == 0) {
      #pragma unroll
      for (int i = 0; i < 4; ++i) {
        int rbase = i * 32 + wave * 8;              // wave-uniform LDS row base (mult of 8)
        int r = rbase + srow;
        gld_lds16(&A[(size_t)(m0 + r) * K + k0 + scol], &As[rbase * BK]);
        gld_lds16(&Bt[(size_t)(n0 + r) * K + k0 + scol], &Bs[rbase * BK]);
      }
    } else {
      #pragma unroll
      for (int i = 0; i < 2; ++i) {                 // A: 64 rows
        int rbase = wave * 16 + i * 8;
        gld_lds16(&A[(size_t)(m0 + rbase + srow) * K + k0 + scol], &As[rbase * BK]);
      }
      #pragma unroll
      for (int i = 0; i < 4; ++i) {                 // B: 128 rows
        int rbase = i * 32 + wave * 8;
        gld_lds16(&Bt[(size_t)(n0 + rbase + srow) * K + k0 + scol], &Bs[rbase * BK]);
      }
    }
    __syncthreads();                                // drains vmcnt (compiler-emitted)
    #pragma unroll
    for (int ks = 0; ks < 2; ++ks) {
      frag_t af[MI], bf[NI];
      #pragma unroll
      for (int mi = 0; mi < MI; ++mi)
        af[mi] = *(const frag_t*)&As[(mbase + mi * 16 + li) * BK + (((ks * 4 + quad) ^ (li & 7)) * 8)];
      #pragma unroll
      for (int ni = 0; ni < NI; ++ni)
        bf[ni] = *(const frag_t*)&Bs[(nbase + ni * 16 + li) * BK + (((ks * 4 + quad) ^ (li & 7)) * 8)];
      #pragma unroll
      for (int mi = 0; mi < MI; ++mi)
        #pragma unroll
        for (int ni = 0; ni < NI; ++ni)
          acc[mi][ni] = __builtin_amdgcn_mfma_f32_16x16x32_bf16(af[mi], bf[ni], acc[mi][ni], 0, 0, 0);
    }
    __syncthreads();
  }
  // epilogue: C/D layout row = quad*4+reg, col = li  [measured m89/m91]
  if (EPI == 1) {
    #pragma unroll
    for (int mi = 0; mi < MI; ++mi)
      #pragma unroll
      for (int ni = 0; ni < NI; ++ni) {
        int gcol = n0 + nbase + ni * 16 + li;
        float bv = bias[gcol];
        #pragma unroll
        for (int r = 0; r < 4; ++r) {
          int grow = m0 + mbase + mi * 16 + quad * 4 + r;
          Co[(size_t)grow * N + gcol] = acc[mi][ni][r] + bv;
        }
      }
  } else {
    int which = (n0 + nbase) >> 10;                 // wave-uniform (64-aligned halves)
    if (which < 2) {                                // Q / K: [bh][s][hd]
      #pragma unroll
      for (int mi = 0; mi < MI; ++mi)
        #pragma unroll
        for (int ni = 0; ni < NI; ++ni) {
          int gcol = n0 + nbase + ni * 16 + li;
          float bv = bias[gcol];
          #pragma unroll
          for (int r = 0; r < 4; ++r) {
            int grow = m0 + mbase + mi * 16 + quad * 4 + r;
            float v = acc[mi][ni][r] + bv;
            int d = gcol & 1023, h = d >> 6, hd = d & 63;
            int b = grow >> 11, s = grow & 2047;
            size_t bh = (size_t)b * H_ + h;
            if (which == 0) Qo[(bh * S_ + s) * HD_ + hd] = f2bf(v * QSCALE);
            else            Ko[(bh * S_ + s) * HD_ + hd] = f2bf(v);
          }
        }
    } else {                                        // V: per-wave LDS transpose -> sigma-permuted V^T
      ushort* vlds = smem + wave * (64 * 72);       // staging LDS dead after last barrier
      #pragma unroll
      for (int ni = 0; ni < NI; ++ni) {
        float bv = bias[n0 + nbase + ni * 16 + li];
        #pragma unroll
        for (int mi = 0; mi < MI; ++mi)
          #pragma unroll
          for (int r = 0; r < 4; ++r)                // col = sigma^-1(o), o = mi*16+quad*4+r
            vlds[(ni * 16 + li) * 72 + 16 * quad + 4 * r + mi] = f2bf(acc[mi][ni][r] + bv);
      }                                             // wave-private: in-order ds, no barrier
      int hgrp = ((n0 & 1023) + nbase) >> 6;
      int b = m0 >> 11;
      int s0 = (m0 & 2047) + mbase;
      size_t vbase = (size_t)(b * H_ + hgrp) * HD_ * S_;
      #pragma unroll
      for (int i = 0; i < 8; ++i) {
        int row = i * 8 + (lane >> 3);              // hd
        int col = (lane & 7) * 8;                   // s offset (permuted), 16B aligned
        *(uint4*)&Vo[vbase + (size_t)row * S_ + s0 + col] = *(const uint4*)&vlds[row * 72 + col];
      }
    }
  }
}

// ---------- causal flash attention ----------
// WG = 4 waves = one 64-row q-tile; double-buffered LDS K/V via async
// global_load_lds; LDS = 40960 B -> 4 WGs/CU. Keys live in the sigma-permuted
// basis (shared with V^T storage): lane's 4 p-values are consecutive permuted
// cols -> one packed ds_write_b64 per row. l computed by MFMA with a
// ones-B (row-sum broadcast across cols: no per-iter adds, no epilogue
// shuffle). Raw v_exp_f32; log2e pre-folded into Q; fixed-max softmax.
__global__ __launch_bounds__(256) void k_attn(
    const ushort* __restrict__ Q, const ushort* __restrict__ K,
    const ushort* __restrict__ Vt, ushort* __restrict__ O) {
  __shared__ ushort Kbuf[2][64 * 64];
  __shared__ ushort Vbuf[2][64 * 64];
  __shared__ ushort Plds[4 * 16 * 64];             // per-wave P buffer (C->A transform)
  int lane = threadIdx.x & 63, wave = threadIdx.x >> 6;
  int quad = lane >> 4, li = lane & 15;
  int bh = blockIdx.x;                             // x = bh: XCD round-robin, K/V hot in L2
  int qb = 31 - (int)blockIdx.y;                   // heavy q-tiles dispatch first
  int b = bh >> 4, h = bh & 15;
  int q0 = qb * 64 + wave * 16;
  const ushort* Qb = Q  + (size_t)bh * S_ * HD_;
  const ushort* Kb = K  + (size_t)bh * S_ * HD_;
  const ushort* Vb = Vt + (size_t)bh * HD_ * S_;
  ushort* Pw = &Plds[wave * 1024];

  frag_t qf[2];  // A-operand: m = li, k = quad*8+j  [measured m120]
  #pragma unroll
  for (int ks = 0; ks < 2; ++ks)
    qf[ks] = *(const frag_t*)&Qb[(size_t)(q0 + li) * HD_ + ks * 32 + quad * 8];

  frag_t ones;                                     // bf16 1.0 splat (B for row-sum MFMA)
  #pragma unroll
  for (int i = 0; i < 8; ++i) ones[i] = (short)0x3F80;

  f32x4 o[4] = {};
  f32x4 lacc = {};                                 // row-sums of P (C-layout, col-broadcast)

  auto stage = [&](int kb, int bi) {
    #pragma unroll
    for (int i = 0; i < 2; ++i) {
      int rt  = wave * 16 + i * 8 + (lane >> 3);   // tile row
      int c16 = (lane & 7) ^ (lane >> 3);          // swizzle: (rt&7) == lane>>3
      gld_lds16(&Kb[(size_t)(kb * 64 + rt) * HD_ + c16 * 8], &Kbuf[bi][(wave * 16 + i * 8) * 64]);
      gld_lds16(&Vb[(size_t)rt * S_ + kb * 64 + c16 * 8],    &Vbuf[bi][(wave * 16 + i * 8) * 64]);
    }
  };

  auto comp = [&](int kb, bool diag, int bi) {
    f32x4 sc[4];
    #pragma unroll
    for (int t = 0; t < 4; ++t) {
      f32x4 a = {};
      #pragma unroll
      for (int ks = 0; ks < 2; ++ks) {
        frag_t kf = *(const frag_t*)&Kbuf[bi][(t * 16 + li) * 64 + (((quad + ks * 4) ^ (li & 7)) * 8)];
        a = __builtin_amdgcn_mfma_f32_16x16x32_bf16(qf[ks], kf, a, 0, 0, 0);
      }
      sc[t] = a;
    }
    if (diag) {
      #pragma unroll
      for (int t = 0; t < 4; ++t) {
        int key = kb * 64 + t * 16 + li;
        #pragma unroll
        for (int r = 0; r < 4; ++r)
          if (key > q0 + quad * 4 + r) sc[t][r] = -1e30f;
      }
    }
    #pragma unroll
    for (int t = 0; t < 4; ++t)
      #pragma unroll
      for (int r = 0; r < 4; ++r)
        sc[t][r] = EXP2(sc[t][r]);                 // masked -> exp2(-1e30) = 0
    #pragma unroll
    for (int r = 0; r < 4; ++r) {                  // pack 4 bf16 (permuted cols 4li..4li+3) -> b64
      int row = quad * 4 + r;
      unsigned a0 = __float_as_uint(sc[0][r]) + 0x8000u;
      unsigned a1 = __float_as_uint(sc[1][r]) + 0x8000u;
      unsigned a2 = __float_as_uint(sc[2][r]) + 0x8000u;
      unsigned a3 = __float_as_uint(sc[3][r]) + 0x8000u;
      uint2 w;
      w.x = (a0 >> 16) | (a1 & 0xFFFF0000u);
      w.y = (a2 >> 16) | (a3 & 0xFFFF0000u);
      *(uint2*)&Pw[row * 64 + ((li ^ (row & 6)) * 4)] = w;
    }
    frag_t pf[2];                                  // wave-private LDS: in-order, no barrier
    #pragma unroll
    for (int ks = 0; ks < 2; ++ks) {
      int g0 = (ks * 4 + quad) * 2;
      pf[ks] = *(const frag_t*)&Pw[li * 64 + ((g0 ^ (li & 6)) * 4)];
    }
    lacc = __builtin_amdgcn_mfma_f32_16x16x32_bf16(pf[0], ones, lacc, 0, 0, 0);
    lacc = __builtin_amdgcn_mfma_f32_16x16x32_bf16(pf[1], ones, lacc, 0, 0, 0);
    #pragma unroll
    for (int t = 0; t < 4; ++t)
      #pragma unroll
      for (int ks = 0; ks < 2; ++ks) {
        frag_t vf = *(const frag_t*)&Vbuf[bi][(t * 16 + li) * 64 + (((quad + ks * 4) ^ (li & 7)) * 8)];
        o[t] = __builtin_amdgcn_mfma_f32_16x16x32_bf16(pf[ks], vf, o[t], 0, 0, 0);
      }
  };

  stage(0, 0);
  __syncthreads();                                 // DMA for kb=0 landed
  for (int kb = 0; kb <= qb; ++kb) {
    if (kb < qb) stage(kb + 1, (kb + 1) & 1);      // async DMA overlaps comp below
    comp(kb, kb == qb, kb & 1);
    __syncthreads();                               // drains DMA + guards buffer reuse
  }

  #pragma unroll
  for (int r = 0; r < 4; ++r) {
    float inv = 1.f / lacc[r];                     // row-sum already broadcast across lanes
    int srow = q0 + quad * 4 + r;
    #pragma unroll
    for (int ht = 0; ht < 4; ++ht)
      O[((size_t)b * S_ + srow) * D_ + h * 64 + ht * 16 + li] = f2bf(o[ht][r] * inv);
  }
}

extern "C" void kernel_launch(void* const* d_in, const int* in_sizes, int n_in,
                              void* d_out, int out_size, void* d_ws, size_t ws_size,
                              hipStream_t stream) {
  (void)in_sizes; (void)n_in; (void)out_size; (void)ws_size;
  const float* x     = (const float*)d_in[0];
  const float* Wqkv  = (const float*)d_in[1];
  const float* bqkv  = (const float*)d_in[2];
  const float* Wproj = (const float*)d_in[3];
  const float* bproj = (const float*)d_in[4];
  float* out = (float*)d_out;

  char* ws = (char*)d_ws;                          // 40 MB used
  ushort* Xbf = (ushort*)(ws);                     //  8 MB  [4096,1024] bf16 (reused as O after attn)
  ushort* Wqt = (ushort*)(ws + (8u  << 20));       //  6 MB  [3072,1024] bf16
  ushort* Wpt = (ushort*)(ws + (14u << 20));       //  2 MB  [1024,1024] bf16
  ushort* Qbf = (ushort*)(ws + (16u << 20));       //  8 MB  [32,2048,64]  (pre-scaled by 0.125*log2e)
  ushort* Kbf = (ushort*)(ws + (24u << 20));       //  8 MB  [32,2048,64]
  ushort* Vtb = (ushort*)(ws + (32u << 20));       //  8 MB  [32,64,2048]  (V^T, sigma-permuted keys)
  ushort* Obf = Xbf;                               // X dead after QKV GEMM

  k_prep<<<dim3(2048), dim3(256), 0, stream>>>(x, Wqkv, Wproj, Xbf, Wqt, Wpt);
  k_gemm<0><<<dim3(24, 32), dim3(256), 0, stream>>>(Xbf, Wqt, bqkv, Qbf, Kbf, Vtb,
                                                    (float*)nullptr, 3 * D_, D_);
  k_attn<<<dim3(B_ * H_, 32), dim3(256), 0, stream>>>(Qbf, Kbf, Vtb, Obf);
  k_gemm<1><<<dim3(8, 64), dim3(256), 0, stream>>>(Obf, Wpt, bproj,
                                                   (ushort*)nullptr, (ushort*)nullptr, (ushort*)nullptr,
                                                   out, D_, D_);
}

// Round 12
// 170.422 us; speedup vs baseline: 1.5880x; 1.0560x over previous
//
#include <hip/hip_runtime.h>

using frag_t = __attribute__((ext_vector_type(8))) short;   // 8 x bf16 (4 VGPRs)
using f32x4  = __attribute__((ext_vector_type(4))) float;   // MFMA C/D

#define L2E 1.4426950408889634f

#if __has_builtin(__builtin_amdgcn_exp2f)
#define EXP2(x) __builtin_amdgcn_exp2f(x)   // raw v_exp_f32 (no denormal fixup seq)
#else
#define EXP2(x) exp2f(x)
#endif

constexpr int B_  = 2, S_ = 2048, D_ = 1024, H_ = 16, HD_ = 64;
constexpr int M_  = B_ * S_;      // 4096
constexpr float QSCALE = 0.125f * L2E;   // fold softmax log2e into Q

__device__ __forceinline__ ushort f2bf(float f) {
  union { float f; unsigned u; } v; v.f = f;
  unsigned u = v.u;
  unsigned r = (u + 0x7FFFu + ((u >> 16) & 1u)) >> 16;  // round-nearest-even
  return (ushort)r;
}
__device__ __forceinline__ unsigned pk_bf2(float a, float b) {  // round-half-up pack
  unsigned ua = __float_as_uint(a) + 0x8000u;
  unsigned ub = __float_as_uint(b) + 0x8000u;
  return (ua >> 16) | (ub & 0xFFFF0000u);
}

// async 16B/lane global->LDS (lds dest = wave-uniform base + lane*16) [m97]
__device__ __forceinline__ void gld_lds16(const ushort* g, ushort* l) {
  __builtin_amdgcn_global_load_lds((const __attribute__((address_space(1))) void*)g,
                                   (__attribute__((address_space(3))) void*)l, 16, 0, 0);
}

// ---------- fused prep: x->bf16  |  Wqkv^T->bf16  |  Wproj^T->bf16 ----------
__global__ __launch_bounds__(256) void k_prep(
    const float* __restrict__ x, const float* __restrict__ Wqkv,
    const float* __restrict__ Wproj,
    ushort* __restrict__ Xbf, ushort* __restrict__ Wqt, ushort* __restrict__ Wpt) {
  int blk = blockIdx.x, tid = threadIdx.x;
  if (blk < 1024) {                                 // x convert: 4096 elems/block
    size_t base = (size_t)blk * 4096 + tid * 4;
    #pragma unroll
    for (int i = 0; i < 4; ++i) {
      float4 f = *(const float4*)(x + base + i * 1024);
      ushort4 o;
      o.x = f2bf(f.x); o.y = f2bf(f.y); o.z = f2bf(f.z); o.w = f2bf(f.w);
      *(ushort4*)(Xbf + base + i * 1024) = o;
    }
  } else {                                          // W [K,N] -> W^T [N,K] bf16, 64x64 tile
    __shared__ float tile[64][65];
    const float* in; ushort* out; int N, K, bx, by;
    if (blk < 1024 + 768) { int b2 = blk - 1024; in = Wqkv;  out = Wqt; N = 3072; K = 1024; bx = b2 % 48; by = b2 / 48; }
    else                  { int b2 = blk - 1792; in = Wproj; out = Wpt; N = 1024; K = 1024; bx = b2 % 16; by = b2 / 16; }
    int n0 = bx * 64, k0 = by * 64;
    int tx = tid & 63, ty = tid >> 6;               // (64,4)
    #pragma unroll
    for (int i = 0; i < 16; ++i)
      tile[ty + i * 4][tx] = in[(size_t)(k0 + ty + i * 4) * N + n0 + tx];
    __syncthreads();
    #pragma unroll
    for (int i = 0; i < 16; ++i)
      out[(size_t)(n0 + ty + i * 4) * K + k0 + tx] = f2bf(tile[tx][ty + i * 4]);
  }
}

// ---------- bf16 MFMA GEMM: C[M,N] = A[M,K] @ Bt[N,K]^T + bias ----------
// Validated m97 single-buffer K-loop + XOR chunk swizzle (32k conflicts, R10).
// R12: BN=64 everywhere — occupancy play. EPI0 grid 48x32=1536 = 6 WG/CU
// (was 3), LDS 24.5KB; EPI1 BM=64,BN=64 grid 16x64=1024 = 4 WG/CU.
// The structural barrier-drain stall hides via inter-WG overlap (m114);
// residency was the binding constraint (Occupancy 14%, grid-limited).
// nbase stays 32-aligned -> 'which' wave-uniform; each wave still owns a
// complete 64-key sigma-block for the V^T transpose (sigma(p)=16(p&3)+(p>>2)).
template <int EPI>
__global__ __launch_bounds__(256) void k_gemm(
    const ushort* __restrict__ A, const ushort* __restrict__ Bt,
    const float* __restrict__ bias,
    ushort* __restrict__ Qo, ushort* __restrict__ Ko, ushort* __restrict__ Vo,
    float* __restrict__ Co, int N, int K) {
  constexpr int BM = (EPI == 0) ? 128 : 64;
  constexpr int BN = 64, BK = 64;
  constexpr int MI = (EPI == 0) ? 4 : 2, NI = 2;
  __shared__ ushort smem[(BM + BN) * BK];           // EPI0 epilogue V-overlay (18KB) fits
  ushort* As = smem;
  ushort* Bs = smem + BM * BK;
  int tid  = threadIdx.x;
  int lane = tid & 63, wave = tid >> 6;
  int quad = lane >> 4, li = lane & 15;
  int mbase = (wave >> 1) * (MI * 16);              // 2x2 waves
  int nbase = (wave & 1) * 32;
  int m0 = blockIdx.y * BM, n0 = blockIdx.x * BN;
  int srow = lane >> 3;                             // within a wave: 8 rows x 128B
  int scol = ((lane & 7) ^ srow) * 8;               // XOR-swizzled global chunk
  f32x4 acc[MI][NI] = {};
  for (int k0 = 0; k0 < K; k0 += BK) {
    if (EPI == 0) {
      #pragma unroll
      for (int i = 0; i < 4; ++i) {                 // A: 128 rows
        int rbase = i * 32 + wave * 8;
        gld_lds16(&A[(size_t)(m0 + rbase + srow) * K + k0 + scol], &As[rbase * BK]);
      }
    } else {
      #pragma unroll
      for (int i = 0; i < 2; ++i) {                 // A: 64 rows
        int rbase = wave * 16 + i * 8;
        gld_lds16(&A[(size_t)(m0 + rbase + srow) * K + k0 + scol], &As[rbase * BK]);
      }
    }
    #pragma unroll
    for (int i = 0; i < 2; ++i) {                   // B: 64 rows
      int rbase = wave * 16 + i * 8;
      gld_lds16(&Bt[(size_t)(n0 + rbase + srow) * K + k0 + scol], &Bs[rbase * BK]);
    }
    __syncthreads();                                // drains vmcnt (compiler-emitted)
    #pragma unroll
    for (int ks = 0; ks < 2; ++ks) {
      frag_t af[MI], bf[NI];
      #pragma unroll
      for (int mi = 0; mi < MI; ++mi)
        af[mi] = *(const frag_t*)&As[(mbase + mi * 16 + li) * BK + (((ks * 4 + quad) ^ (li & 7)) * 8)];
      #pragma unroll
      for (int ni = 0; ni < NI; ++ni)
        bf[ni] = *(const frag_t*)&Bs[(nbase + ni * 16 + li) * BK + (((ks * 4 + quad) ^ (li & 7)) * 8)];
      #pragma unroll
      for (int mi = 0; mi < MI; ++mi)
        #pragma unroll
        for (int ni = 0; ni < NI; ++ni)
          acc[mi][ni] = __builtin_amdgcn_mfma_f32_16x16x32_bf16(af[mi], bf[ni], acc[mi][ni], 0, 0, 0);
    }
    __syncthreads();
  }
  // epilogue: C/D layout row = quad*4+reg, col = li  [measured m89/m91]
  if (EPI == 1) {
    #pragma unroll
    for (int mi = 0; mi < MI; ++mi)
      #pragma unroll
      for (int ni = 0; ni < NI; ++ni) {
        int gcol = n0 + nbase + ni * 16 + li;
        float bv = bias[gcol];
        #pragma unroll
        for (int r = 0; r < 4; ++r) {
          int grow = m0 + mbase + mi * 16 + quad * 4 + r;
          Co[(size_t)grow * N + gcol] = acc[mi][ni][r] + bv;
        }
      }
  } else {
    int which = (n0 + nbase) >> 10;                 // wave-uniform (32-aligned span of 32)
    if (which < 2) {                                // Q / K: [bh][s][hd]
      #pragma unroll
      for (int mi = 0; mi < MI; ++mi)
        #pragma unroll
        for (int ni = 0; ni < NI; ++ni) {
          int gcol = n0 + nbase + ni * 16 + li;
          float bv = bias[gcol];
          #pragma unroll
          for (int r = 0; r < 4; ++r) {
            int grow = m0 + mbase + mi * 16 + quad * 4 + r;
            float v = acc[mi][ni][r] + bv;
            int d = gcol & 1023, h = d >> 6, hd = d & 63;
            int b = grow >> 11, s = grow & 2047;
            size_t bh = (size_t)b * H_ + h;
            if (which == 0) Qo[(bh * S_ + s) * HD_ + hd] = f2bf(v * QSCALE);
            else            Ko[(bh * S_ + s) * HD_ + hd] = f2bf(v);
          }
        }
    } else {                                        // V: per-wave LDS transpose -> sigma-permuted V^T
      ushort* vlds = smem + wave * (32 * 72);       // 32 hd-rows x 64 s (+8 pad); staging dead
      #pragma unroll
      for (int ni = 0; ni < NI; ++ni) {
        float bv = bias[n0 + nbase + ni * 16 + li];
        #pragma unroll
        for (int mi = 0; mi < MI; ++mi)
          #pragma unroll
          for (int r = 0; r < 4; ++r)               // col = sigma^-1(o), o = mi*16+quad*4+r
            vlds[(ni * 16 + li) * 72 + 16 * quad + 4 * r + mi] = f2bf(acc[mi][ni][r] + bv);
      }                                             // wave-private: in-order ds, no barrier
      int hgrp = (((n0 & 1023) + nbase) >> 6);
      int hd0  = (n0 + nbase) & 63;                 // 0 or 32 within the head
      int b = m0 >> 11;
      int s0 = (m0 & 2047) + mbase;                 // wave's 64-key block (64-aligned)
      size_t vbase = (size_t)(b * H_ + hgrp) * HD_ * S_;
      #pragma unroll
      for (int i = 0; i < 4; ++i) {
        int row = i * 8 + (lane >> 3);              // hd offset (0..31)
        int col = (lane & 7) * 8;                   // s offset (permuted), 16B aligned
        *(uint4*)&Vo[vbase + (size_t)(hd0 + row) * S_ + s0 + col] = *(const uint4*)&vlds[row * 72 + col];
      }
    }
  }
}

// ---------- causal flash attention (validated R10 version) ----------
// WG = 4 waves = one 64-row q-tile; double-buffered LDS K/V via async
// global_load_lds; LDS = 40960 B -> 4 WGs/CU. sigma-permuted key basis
// (shared with V^T): lane's 4 p-values pack to one ds_write_b64/row.
// l via MFMA ones-B (row-sum broadcast). Raw v_exp_f32; log2e in Q.
__global__ __launch_bounds__(256) void k_attn(
    const ushort* __restrict__ Q, const ushort* __restrict__ K,
    const ushort* __restrict__ Vt, ushort* __restrict__ O) {
  __shared__ ushort Kbuf[2][64 * 64];
  __shared__ ushort Vbuf[2][64 * 64];
  __shared__ ushort Plds[4 * 16 * 64];             // per-wave P buffer (C->A transform)
  int lane = threadIdx.x & 63, wave = threadIdx.x >> 6;
  int quad = lane >> 4, li = lane & 15;
  int bh = blockIdx.x;                             // x = bh: XCD round-robin, K/V hot in L2
  int qb = 31 - (int)blockIdx.y;                   // heavy q-tiles dispatch first
  int b = bh >> 4, h = bh & 15;
  int q0 = qb * 64 + wave * 16;
  const ushort* Qb = Q  + (size_t)bh * S_ * HD_;
  const ushort* Kb = K  + (size_t)bh * S_ * HD_;
  const ushort* Vb = Vt + (size_t)bh * HD_ * S_;
  ushort* Pw = &Plds[wave * 1024];

  frag_t qf[2];  // A-operand: m = li, k = quad*8+j  [measured m120]
  #pragma unroll
  for (int ks = 0; ks < 2; ++ks)
    qf[ks] = *(const frag_t*)&Qb[(size_t)(q0 + li) * HD_ + ks * 32 + quad * 8];

  frag_t ones;                                     // bf16 1.0 splat (B for row-sum MFMA)
  #pragma unroll
  for (int i = 0; i < 8; ++i) ones[i] = (short)0x3F80;

  f32x4 o[4] = {};
  f32x4 lacc = {};                                 // row-sums of P (C-layout, col-broadcast)

  auto stage = [&](int kb, int bi) {
    #pragma unroll
    for (int i = 0; i < 2; ++i) {
      int rt  = wave * 16 + i * 8 + (lane >> 3);   // tile row
      int c16 = (lane & 7) ^ (lane >> 3);          // swizzle: (rt&7) == lane>>3
      gld_lds16(&Kb[(size_t)(kb * 64 + rt) * HD_ + c16 * 8], &Kbuf[bi][(wave * 16 + i * 8) * 64]);
      gld_lds16(&Vb[(size_t)rt * S_ + kb * 64 + c16 * 8],    &Vbuf[bi][(wave * 16 + i * 8) * 64]);
    }
  };

  auto comp = [&](int kb, bool diag, int bi) {
    f32x4 sc[4];
    #pragma unroll
    for (int t = 0; t < 4; ++t) {
      f32x4 a = {};
      #pragma unroll
      for (int ks = 0; ks < 2; ++ks) {
        frag_t kf = *(const frag_t*)&Kbuf[bi][(t * 16 + li) * 64 + (((quad + ks * 4) ^ (li & 7)) * 8)];
        a = __builtin_amdgcn_mfma_f32_16x16x32_bf16(qf[ks], kf, a, 0, 0, 0);
      }
      sc[t] = a;
    }
    if (diag) {
      #pragma unroll
      for (int t = 0; t < 4; ++t) {
        int key = kb * 64 + t * 16 + li;
        #pragma unroll
        for (int r = 0; r < 4; ++r)
          if (key > q0 + quad * 4 + r) sc[t][r] = -1e30f;
      }
    }
    #pragma unroll
    for (int t = 0; t < 4; ++t)
      #pragma unroll
      for (int r = 0; r < 4; ++r)
        sc[t][r] = EXP2(sc[t][r]);                 // masked -> exp2(-1e30) = 0
    #pragma unroll
    for (int r = 0; r < 4; ++r) {                  // pack 4 bf16 (permuted cols 4li..4li+3) -> b64
      int row = quad * 4 + r;
      uint2 w;
      w.x = pk_bf2(sc[0][r], sc[1][r]);
      w.y = pk_bf2(sc[2][r], sc[3][r]);
      *(uint2*)&Pw[row * 64 + ((li ^ (row & 6)) * 4)] = w;
    }
    frag_t pf[2];                                  // wave-private LDS: in-order, no barrier
    #pragma unroll
    for (int ks = 0; ks < 2; ++ks) {
      int g0 = (ks * 4 + quad) * 2;
      pf[ks] = *(const frag_t*)&Pw[li * 64 + ((g0 ^ (li & 6)) * 4)];
    }
    lacc = __builtin_amdgcn_mfma_f32_16x16x32_bf16(pf[0], ones, lacc, 0, 0, 0);
    lacc = __builtin_amdgcn_mfma_f32_16x16x32_bf16(pf[1], ones, lacc, 0, 0, 0);
    #pragma unroll
    for (int t = 0; t < 4; ++t)
      #pragma unroll
      for (int ks = 0; ks < 2; ++ks) {
        frag_t vf = *(const frag_t*)&Vbuf[bi][(t * 16 + li) * 64 + (((quad + ks * 4) ^ (li & 7)) * 8)];
        o[t] = __builtin_amdgcn_mfma_f32_16x16x32_bf16(pf[ks], vf, o[t], 0, 0, 0);
      }
  };

  stage(0, 0);
  __syncthreads();                                 // DMA for kb=0 landed
  for (int kb = 0; kb <= qb; ++kb) {
    if (kb < qb) stage(kb + 1, (kb + 1) & 1);      // async DMA overlaps comp below
    comp(kb, kb == qb, kb & 1);
    __syncthreads();                               // drains DMA + guards buffer reuse
  }

  #pragma unroll
  for (int r = 0; r < 4; ++r) {
    float inv = 1.f / lacc[r];                     // row-sum already broadcast across lanes
    int srow = q0 + quad * 4 + r;
    #pragma unroll
    for (int ht = 0; ht < 4; ++ht)
      O[((size_t)b * S_ + srow) * D_ + h * 64 + ht * 16 + li] = f2bf(o[ht][r] * inv);
  }
}

extern "C" void kernel_launch(void* const* d_in, const int* in_sizes, int n_in,
                              void* d_out, int out_size, void* d_ws, size_t ws_size,
                              hipStream_t stream) {
  (void)in_sizes; (void)n_in; (void)out_size; (void)ws_size;
  const float* x     = (const float*)d_in[0];
  const float* Wqkv  = (const float*)d_in[1];
  const float* bqkv  = (const float*)d_in[2];
  const float* Wproj = (const float*)d_in[3];
  const float* bproj = (const float*)d_in[4];
  float* out = (float*)d_out;

  char* ws = (char*)d_ws;                          // 40 MB used
  ushort* Xbf = (ushort*)(ws);                     //  8 MB  [4096,1024] bf16 (reused as O after attn)
  ushort* Wqt = (ushort*)(ws + (8u  << 20));       //  6 MB  [3072,1024] bf16
  ushort* Wpt = (ushort*)(ws + (14u << 20));       //  2 MB  [1024,1024] bf16
  ushort* Qbf = (ushort*)(ws + (16u << 20));       //  8 MB  [32,2048,64]  (pre-scaled by 0.125*log2e)
  ushort* Kbf = (ushort*)(ws + (24u << 20));       //  8 MB  [32,2048,64]
  ushort* Vtb = (ushort*)(ws + (32u << 20));       //  8 MB  [32,64,2048]  (V^T, sigma-permuted keys)
  ushort* Obf = Xbf;                               // X dead after QKV GEMM

  k_prep<<<dim3(2048), dim3(256), 0, stream>>>(x, Wqkv, Wproj, Xbf, Wqt, Wpt);
  k_gemm<0><<<dim3(48, 32), dim3(256), 0, stream>>>(Xbf, Wqt, bqkv, Qbf, Kbf, Vtb,
                                                    (float*)nullptr, 3 * D_, D_);
  k_attn<<<dim3(B_ * H_, 32), dim3(256), 0, stream>>>(Qbf, Kbf, Vtb, Obf);
  k_gemm<1><<<dim3(16, 64), dim3(256), 0, stream>>>(Obf, Wpt, bproj,
                                                    (ushort*)nullptr, (ushort*)nullptr, (ushort*)nullptr,
                                                    out, D_, D_);
}